// Round 5
// baseline (102.340 us; speedup 1.0000x reference)
//
#include <hip/hip_runtime.h>
#include <math.h>

#define NB 16
#define NL 4096
#define NC 512
#define NC4 128          // NC/4 float4 per row
#define NKEEP 2458       // ceil(4096*0.6)

typedef float f32x4 __attribute__((ext_vector_type(4)));

// ---------------- ws layout ----------------
// key     u64 [NB][NL]        @ 0        (512 KB)
// rank    i32 [NB][NL]        @ 524288   (256 KB)
// w       f32 [NB][NL]        @ 786432   (256 KB)  (unnormalized exp, 0 for keep rows)
// partial f32 [NB*128][512]   @ 1048576  (4 MB)    (per-block extra partial sums)
// scalars                     @ 5242880  : alpha[16] beta[16] smaxu[16](u32) Z[16]

// Kernel 1: bit-exact replica of np.float32 pairwise mean (PW_BLOCKSIZE=128,
// 8-accumulator base case, balanced binary combine == butterfly), then
// coverage/sigmoid. One wave per batch; lanes 0..31 own 128-elem base blocks.
__global__ void __launch_bounds__(64) k_alpha(const float* __restrict__ ax,
                                              const float* __restrict__ ay,
                                              float* __restrict__ alpha,
                                              float* __restrict__ beta) {
  int b = blockIdx.x;
  int lane = threadIdx.x;
  float sx = 0.0f, sy = 0.0f;
  if (lane < 32) {
    const float* px = ax + b * NL + lane * 128;
    const float* py = ay + b * NL + lane * 128;
    float r[8], q[8];
#pragma unroll
    for (int j = 0; j < 8; ++j) { r[j] = px[j]; q[j] = py[j]; }
    for (int i = 8; i < 128; i += 8) {
#pragma unroll
      for (int j = 0; j < 8; ++j) {
        r[j] = __fadd_rn(r[j], px[i + j]);
        q[j] = __fadd_rn(q[j], py[i + j]);
      }
    }
    sx = __fadd_rn(__fadd_rn(__fadd_rn(r[0], r[1]), __fadd_rn(r[2], r[3])),
                   __fadd_rn(__fadd_rn(r[4], r[5]), __fadd_rn(r[6], r[7])));
    sy = __fadd_rn(__fadd_rn(__fadd_rn(q[0], q[1]), __fadd_rn(q[2], q[3])),
                   __fadd_rn(__fadd_rn(q[4], q[5]), __fadd_rn(q[6], q[7])));
  }
#pragma unroll
  for (int m = 1; m <= 16; m <<= 1) {
    sx = __fadd_rn(sx, __shfl_xor(sx, m, 64));
    sy = __fadd_rn(sy, __shfl_xor(sy, m, 64));
  }
  if (lane == 0) {
    float mx = __fdiv_rn(sx, 4096.0f);
    float my = __fdiv_rn(sy, 4096.0f);
    float cov = __fdiv_rn(my, __fadd_rn(mx, 1e-6f));
    float z = __fsub_rn(1.0f, cov);
    double a = 1.0 / (1.0 + exp(-(double)z));   // correctly-rounded sigmoid
    float af = (float)a;
    alpha[b] = af;
    beta[b] = __fsub_rn(1.0f, af);
  }
}

// Kernel 2: composite sort keys (mul,mul,add, no FMA, matches np), zero rank,
// and per-batch score max via wave-reduce + deterministic atomicMax on the
// monotone sortable-uint.
__global__ void __launch_bounds__(256) k_keys(const float* __restrict__ ax,
                                              const float* __restrict__ ay,
                                              const float* __restrict__ alpha,
                                              const float* __restrict__ beta,
                                              unsigned long long* __restrict__ key,
                                              int* __restrict__ rank,
                                              unsigned* __restrict__ smaxu) {
  int idx = blockIdx.x * 256 + threadIdx.x;   // 65536
  int b = idx >> 12;
  int l = idx & (NL - 1);
  float s = __fadd_rn(__fmul_rn(alpha[b], ax[idx]), __fmul_rn(beta[b], ay[idx]));
  unsigned u = __float_as_uint(s);
  unsigned su = u ^ ((u & 0x80000000u) ? 0xFFFFFFFFu : 0x80000000u); // ascending map
  unsigned du = ~su;                                                 // descending
  key[idx] = ((unsigned long long)du << 32) | (unsigned)l;           // stable tiebreak
  rank[idx] = 0;
  unsigned m = su;
#pragma unroll
  for (int d = 1; d < 64; d <<= 1) {
    unsigned o = (unsigned)__shfl_xor((int)m, d, 64);
    m = (o > m) ? o : m;
  }
  if ((threadIdx.x & 63) == 0) atomicMax(&smaxu[b], m);  // max: deterministic
}

// Kernel 3: rank(i) = #{j : key_j < key_i}. Register-blocked: 4 i-keys/thread,
// 512-key j-tile in LDS read as broadcast ulonglong2. grid (4, 8, NB).
__global__ void __launch_bounds__(256) k_rank(const unsigned long long* __restrict__ key,
                                              int* __restrict__ rank) {
  __shared__ unsigned long long tile[512];
  int b = blockIdx.z;
  int tid = threadIdx.x;
  const unsigned long long* kb = key + b * NL;
  int ibase = blockIdx.x * 1024;
  unsigned long long ki[4];
#pragma unroll
  for (int k = 0; k < 4; ++k) ki[k] = kb[ibase + k * 256 + tid];
  int j0 = blockIdx.y * 512;
  tile[tid] = kb[j0 + tid];
  tile[tid + 256] = kb[j0 + 256 + tid];
  __syncthreads();
  const ulonglong2* t2 = (const ulonglong2*)tile;
  int cnt[4] = {0, 0, 0, 0};
#pragma unroll 8
  for (int jj = 0; jj < 256; ++jj) {
    ulonglong2 p = t2[jj];
#pragma unroll
    for (int k = 0; k < 4; ++k) {
      cnt[k] += (p.x < ki[k]) ? 1 : 0;
      cnt[k] += (p.y < ki[k]) ? 1 : 0;
    }
  }
#pragma unroll
  for (int k = 0; k < 4; ++k)
    atomicAdd(&rank[b * NL + ibase + k * 256 + tid], cnt[k]);
}

// Kernel 4: mask, unnormalized w = exp(s - smax) for tail rows, Z accumulation.
__global__ void __launch_bounds__(256) k_post(const float* __restrict__ ax,
                                              const float* __restrict__ ay,
                                              const float* __restrict__ alpha,
                                              const float* __restrict__ beta,
                                              const int* __restrict__ rank,
                                              const unsigned* __restrict__ smaxu,
                                              float* __restrict__ w,
                                              float* __restrict__ mask_out,
                                              float* __restrict__ Z) {
  int idx = blockIdx.x * 256 + threadIdx.x;
  int b = idx >> 12;
  int r = rank[idx];
  float s = __fadd_rn(__fmul_rn(alpha[b], ax[idx]), __fmul_rn(beta[b], ay[idx]));
  mask_out[idx] = (r < NKEEP) ? 1.0f : 0.0f;
  unsigned SU = smaxu[b];
  float smax = (SU & 0x80000000u) ? __uint_as_float(SU ^ 0x80000000u)
                                  : __uint_as_float(~SU);
  float wi = (r >= NKEEP) ? expf(s - smax) : 0.0f;
  w[idx] = wi;
  float ws = wi;
#pragma unroll
  for (int d = 1; d < 64; d <<= 1) ws += __shfl_xor(ws, d, 64);
  if ((threadIdx.x & 63) == 0) atomicAdd(&Z[b], ws);
}

// Kernel 5: the permute. STREAMING nontemporal reads (32 consecutive source
// rows/block, 16 independent loads in flight/thread), plain cached scattered
// stores to sel[rank], tail rows FMA-accumulated into per-block partials
// (deterministic, no atomics). grid (128, NB), 256 threads.
__global__ void __launch_bounds__(256) k_big(const f32x4* __restrict__ tok,
                                             const int* __restrict__ rank,
                                             const float* __restrict__ w,
                                             f32x4* __restrict__ sel,
                                             f32x4* __restrict__ partial) {
  int b = blockIdx.y;
  int row0 = blockIdx.x * 32;
  int tid = threadIdx.x;
  int col = tid & 127;
  int g = tid >> 7;              // rows g*16 .. g*16+15
  __shared__ int rsh[32];
  __shared__ float wsh[32];
  __shared__ float accsh[512];
  if (tid < 32) {
    int idx = b * NL + row0 + tid;
    rsh[tid] = rank[idx];
    wsh[tid] = w[idx];
  }
  __syncthreads();

  const f32x4* src = tok + (size_t)(b * NL + row0 + g * 16) * NC4 + col;
  f32x4 v[16];
#pragma unroll
  for (int k = 0; k < 16; ++k)
    v[k] = __builtin_nontemporal_load(&src[(size_t)k * NC4]);

  f32x4* selb = sel + (size_t)b * NKEEP * NC4 + col;
  float ax_ = 0.f, ay_ = 0.f, az_ = 0.f, aw_ = 0.f;
#pragma unroll
  for (int k = 0; k < 16; ++k) {
    int row = g * 16 + k;
    int r = rsh[row];            // wave-uniform
    if (r < NKEEP) {
      selb[(size_t)r * NC4] = v[k];   // plain store: L2 absorbs the scatter
    } else {
      float wk = wsh[row];
      ax_ = fmaf(wk, v[k].x, ax_);
      ay_ = fmaf(wk, v[k].y, ay_);
      az_ = fmaf(wk, v[k].z, az_);
      aw_ = fmaf(wk, v[k].w, aw_);
    }
  }

  if (g == 1) {
    accsh[col * 4 + 0] = ax_; accsh[col * 4 + 1] = ay_;
    accsh[col * 4 + 2] = az_; accsh[col * 4 + 3] = aw_;
  }
  __syncthreads();
  if (g == 0) {
    f32x4 o;
    o.x = ax_ + accsh[col * 4 + 0];
    o.y = ay_ + accsh[col * 4 + 1];
    o.z = az_ + accsh[col * 4 + 2];
    o.w = aw_ + accsh[col * 4 + 3];
    partial[(size_t)(b * 128 + blockIdx.x) * 128 + col] = o;  // unconditional
  }
}

// Kernel 6: extra = (sum of 128 partials) / Z. grid (8, NB), 64 threads.
__global__ void __launch_bounds__(64) k_div(const float* __restrict__ partial,
                                            const float* __restrict__ Z,
                                            float* __restrict__ extra) {
  int b = blockIdx.y;
  int c = blockIdx.x * 64 + threadIdx.x;    // 0..511
  const float* p = partial + (size_t)b * 128 * 512 + c;
  float a0 = 0.f, a1 = 0.f, a2 = 0.f, a3 = 0.f;
#pragma unroll
  for (int j = 0; j < 128; j += 4) {
    a0 += p[(size_t)(j + 0) * 512];
    a1 += p[(size_t)(j + 1) * 512];
    a2 += p[(size_t)(j + 2) * 512];
    a3 += p[(size_t)(j + 3) * 512];
  }
  extra[b * NC + c] = ((a0 + a1) + (a2 + a3)) / Z[b];
}

extern "C" void kernel_launch(void* const* d_in, const int* in_sizes, int n_in,
                              void* d_out, int out_size, void* d_ws, size_t ws_size,
                              hipStream_t stream) {
  (void)in_sizes; (void)n_in; (void)out_size; (void)ws_size;
  const f32x4* tok = (const f32x4*)d_in[0];
  const float* ax = (const float*)d_in[1];
  const float* ay = (const float*)d_in[2];

  unsigned long long* key = (unsigned long long*)d_ws;
  int* rank = (int*)((char*)d_ws + 524288);
  float* w = (float*)((char*)d_ws + 786432);
  f32x4* partial = (f32x4*)((char*)d_ws + 1048576);
  float* scalars = (float*)((char*)d_ws + 5242880);
  float* alpha = scalars;
  float* beta = scalars + 16;
  unsigned* smaxu = (unsigned*)(scalars + 32);
  float* Z = scalars + 48;

  float* out = (float*)d_out;
  f32x4* sel = (f32x4*)out;                         // [16][2458][512]
  float* extra = out + (size_t)NB * NKEEP * NC;     // [16][1][512]
  float* mask = extra + (size_t)NB * NC;            // [16][4096]

  (void)hipMemsetAsync(scalars, 0, 256, stream);    // smaxu + Z must start at 0

  k_alpha<<<NB, 64, 0, stream>>>(ax, ay, alpha, beta);
  k_keys<<<256, 256, 0, stream>>>(ax, ay, alpha, beta, key, rank, smaxu);
  k_rank<<<dim3(4, 8, NB), 256, 0, stream>>>(key, rank);
  k_post<<<256, 256, 0, stream>>>(ax, ay, alpha, beta, rank, smaxu, w, mask, Z);
  k_big<<<dim3(128, NB), 256, 0, stream>>>(tok, rank, w, sel, (f32x4*)partial);
  k_div<<<dim3(8, NB), 64, 0, stream>>>((const float*)partial, Z, extra);
}

// Round 6
// 67.764 us; speedup vs baseline: 1.5102x; 1.5102x over previous
//
#include <hip/hip_runtime.h>
#include <math.h>

#define NB 16
#define NL 4096
#define NC 512
#define NC4 128          // NC/4 float4 per row
#define NKEEP 2458       // ceil(4096*0.6)
#define KEEPB 76         // first k_perm block with tail rows (76*32 = 2432)
#define NTAILB 52        // 128 - 76 partial slots per batch

typedef float f32x4 __attribute__((ext_vector_type(4)));

// ---------------- ws layout ----------------
// key     u64 [NB][NL]          @ 0        (512 KB)
// rank    i32 [NB][NL]          @ 524288   (256 KB)
// w       f32 [NB][NL]          @ 786432   (256 KB) unnormalized exp, 0 for keep
// order   i32 [NB][NL]          @ 1048576  (256 KB) inverse permutation
// partial f32 [NB][52][512]     @ 1310720  (1.66 MB)
// scalars                       @ 3145728  alpha[16] beta[16] smaxu[16] Zpart[256]

// Kernel 1: per-batch front-end. Wave 0: bit-exact np pairwise mean
// (PW_BLOCKSIZE=128, 8-acc base, butterfly combine) -> alpha/beta.
// Then all 1024 threads: sort keys (mul,mul,add, no FMA), zero rank,
// block-reduce score max -> smaxu (plain store, no atomics).
__global__ void __launch_bounds__(1024) k_front(const float* __restrict__ ax,
                                                const float* __restrict__ ay,
                                                unsigned long long* __restrict__ key,
                                                int* __restrict__ rank,
                                                float* __restrict__ alpha,
                                                float* __restrict__ beta,
                                                unsigned* __restrict__ smaxu) {
  int b = blockIdx.x;
  int tid = threadIdx.x;
  __shared__ float s_ab[2];
  __shared__ unsigned redmaxu[16];
  if (tid < 64) {
    int lane = tid;
    float sx = 0.0f, sy = 0.0f;
    if (lane < 32) {
      const float* px = ax + b * NL + lane * 128;
      const float* py = ay + b * NL + lane * 128;
      float r[8], q[8];
#pragma unroll
      for (int j = 0; j < 8; ++j) { r[j] = px[j]; q[j] = py[j]; }
      for (int i = 8; i < 128; i += 8) {
#pragma unroll
        for (int j = 0; j < 8; ++j) {
          r[j] = __fadd_rn(r[j], px[i + j]);
          q[j] = __fadd_rn(q[j], py[i + j]);
        }
      }
      sx = __fadd_rn(__fadd_rn(__fadd_rn(r[0], r[1]), __fadd_rn(r[2], r[3])),
                     __fadd_rn(__fadd_rn(r[4], r[5]), __fadd_rn(r[6], r[7])));
      sy = __fadd_rn(__fadd_rn(__fadd_rn(q[0], q[1]), __fadd_rn(q[2], q[3])),
                     __fadd_rn(__fadd_rn(q[4], q[5]), __fadd_rn(q[6], q[7])));
    }
#pragma unroll
    for (int m = 1; m <= 16; m <<= 1) {
      sx = __fadd_rn(sx, __shfl_xor(sx, m, 64));
      sy = __fadd_rn(sy, __shfl_xor(sy, m, 64));
    }
    if (lane == 0) {
      float mx = __fdiv_rn(sx, 4096.0f);
      float my = __fdiv_rn(sy, 4096.0f);
      float cov = __fdiv_rn(my, __fadd_rn(mx, 1e-6f));
      float z = __fsub_rn(1.0f, cov);
      double a = 1.0 / (1.0 + exp(-(double)z));   // correctly-rounded sigmoid
      float af = (float)a;
      alpha[b] = af;
      beta[b] = __fsub_rn(1.0f, af);
      s_ab[0] = af;
      s_ab[1] = __fsub_rn(1.0f, af);
    }
  }
  __syncthreads();
  float af = s_ab[0], bf = s_ab[1];
  unsigned m = 0;   // real max su > 0x80000000 (max score > 0), so 0 is safe
#pragma unroll
  for (int p = 0; p < 4; ++p) {
    int l = p * 1024 + tid;
    int idx = b * NL + l;
    float s = __fadd_rn(__fmul_rn(af, ax[idx]), __fmul_rn(bf, ay[idx]));
    unsigned u = __float_as_uint(s);
    unsigned su = u ^ ((u & 0x80000000u) ? 0xFFFFFFFFu : 0x80000000u);
    key[idx] = ((unsigned long long)(~su) << 32) | (unsigned)l;  // stable descending
    rank[idx] = 0;
    m = (su > m) ? su : m;
  }
#pragma unroll
  for (int d = 1; d < 64; d <<= 1) {
    unsigned o = (unsigned)__shfl_xor((int)m, d, 64);
    m = (o > m) ? o : m;
  }
  if ((tid & 63) == 0) redmaxu[tid >> 6] = m;
  __syncthreads();
  if (tid == 0) {
    unsigned M = redmaxu[0];
#pragma unroll
    for (int k = 1; k < 16; ++k) M = (redmaxu[k] > M) ? redmaxu[k] : M;
    smaxu[b] = M;
  }
}

// Kernel 2: rank(i) = #{j : key_j < key_i}. Register-blocked 4 i-keys/thread,
// 512-key j-tile in LDS read as broadcast ulonglong2. grid (4, 8, NB).
__global__ void __launch_bounds__(256) k_rank(const unsigned long long* __restrict__ key,
                                              int* __restrict__ rank) {
  __shared__ unsigned long long tile[512];
  int b = blockIdx.z;
  int tid = threadIdx.x;
  const unsigned long long* kb = key + b * NL;
  int ibase = blockIdx.x * 1024;
  unsigned long long ki[4];
#pragma unroll
  for (int k = 0; k < 4; ++k) ki[k] = kb[ibase + k * 256 + tid];
  int j0 = blockIdx.y * 512;
  tile[tid] = kb[j0 + tid];
  tile[tid + 256] = kb[j0 + 256 + tid];
  __syncthreads();
  const ulonglong2* t2 = (const ulonglong2*)tile;
  int cnt[4] = {0, 0, 0, 0};
#pragma unroll 8
  for (int jj = 0; jj < 256; ++jj) {
    ulonglong2 p = t2[jj];
#pragma unroll
    for (int k = 0; k < 4; ++k) {
      cnt[k] += (p.x < ki[k]) ? 1 : 0;
      cnt[k] += (p.y < ki[k]) ? 1 : 0;
    }
  }
#pragma unroll
  for (int k = 0; k < 4; ++k)
    atomicAdd(&rank[b * NL + ibase + k * 256 + tid], cnt[k]);
}

// Kernel 3: mask, w = exp(s - smax) (0 for keep), order inversion, and
// deterministic per-block Z partials (no fp atomics). 256 blocks x 256.
__global__ void __launch_bounds__(256) k_mid(const float* __restrict__ ax,
                                             const float* __restrict__ ay,
                                             const float* __restrict__ alpha,
                                             const float* __restrict__ beta,
                                             const int* __restrict__ rank,
                                             const unsigned* __restrict__ smaxu,
                                             float* __restrict__ w,
                                             float* __restrict__ mask_out,
                                             int* __restrict__ order,
                                             float* __restrict__ Zpart) {
  int gid = blockIdx.x * 256 + threadIdx.x;
  int b = gid >> 12;
  int l = gid & (NL - 1);
  int r = rank[gid];
  float s = __fadd_rn(__fmul_rn(alpha[b], ax[gid]), __fmul_rn(beta[b], ay[gid]));
  mask_out[gid] = (r < NKEEP) ? 1.0f : 0.0f;
  unsigned SU = smaxu[b];
  float smax = (SU & 0x80000000u) ? __uint_as_float(SU ^ 0x80000000u)
                                  : __uint_as_float(~SU);
  float wi = (r >= NKEEP) ? expf(s - smax) : 0.0f;
  w[gid] = wi;
  order[b * NL + r] = l;
  float zs = wi;
#pragma unroll
  for (int d = 1; d < 64; d <<= 1) zs += __shfl_xor(zs, d, 64);
  __shared__ float zred[4];
  if ((threadIdx.x & 63) == 0) zred[threadIdx.x >> 6] = zs;
  __syncthreads();
  if (threadIdx.x == 0)
    Zpart[blockIdx.x] = (zred[0] + zred[1]) + (zred[2] + zred[3]);
}

// Kernel 4: the permute, output-centric (R4 direction). Block owns 32
// consecutive OUTPUT positions: gathered cached reads (16 independent loads
// in flight/thread), perfectly streaming 64 KB writes. Positions >= NKEEP
// accumulate w-weighted rows into per-block partial slabs. grid (128, NB).
__global__ void __launch_bounds__(256) k_perm(const f32x4* __restrict__ tok,
                                              const int* __restrict__ order,
                                              const float* __restrict__ w,
                                              f32x4* __restrict__ sel,
                                              f32x4* __restrict__ partial) {
  int b = blockIdx.y;
  int bx = blockIdx.x;
  int p0 = bx * 32;
  int tid = threadIdx.x;
  int col = tid & 127;
  int g = tid >> 7;            // rows p0+g*16 .. p0+g*16+15
  __shared__ int ssrc[32];
  __shared__ float swt[32];
  __shared__ float accsh[512];
  if (tid < 32) {
    int p = p0 + tid;
    int src = order[b * NL + p];
    ssrc[tid] = src;
    swt[tid] = w[b * NL + src];    // 0 for keep rows
  }
  __syncthreads();

  const f32x4* tb = tok + (size_t)b * NL * NC4 + col;
  f32x4 v[16];
#pragma unroll
  for (int k = 0; k < 16; ++k)
    v[k] = tb[(size_t)ssrc[g * 16 + k] * NC4];

  f32x4* sb = sel + (size_t)b * NKEEP * NC4 + col;
  float a0 = 0.f, a1 = 0.f, a2 = 0.f, a3 = 0.f;
#pragma unroll
  for (int k = 0; k < 16; ++k) {
    int p = p0 + g * 16 + k;
    if (p < NKEEP) {
      sb[(size_t)p * NC4] = v[k];          // streaming contiguous writes
    } else {
      float wk = swt[g * 16 + k];
      a0 = fmaf(wk, v[k].x, a0);
      a1 = fmaf(wk, v[k].y, a1);
      a2 = fmaf(wk, v[k].z, a2);
      a3 = fmaf(wk, v[k].w, a3);
    }
  }

  if (bx >= KEEPB) {                        // uniform per block
    if (g == 1) {
      accsh[col * 4 + 0] = a0; accsh[col * 4 + 1] = a1;
      accsh[col * 4 + 2] = a2; accsh[col * 4 + 3] = a3;
    }
    __syncthreads();
    if (g == 0) {
      f32x4 o;
      o.x = a0 + accsh[col * 4 + 0];
      o.y = a1 + accsh[col * 4 + 1];
      o.z = a2 + accsh[col * 4 + 2];
      o.w = a3 + accsh[col * 4 + 3];
      partial[(size_t)(b * NTAILB + (bx - KEEPB)) * 128 + col] = o;
    }
  }
}

// Kernel 5: extra = (sum of 52 partials) / (sum of 16 Z partials). 16 x 512.
__global__ void __launch_bounds__(512) k_back(const float* __restrict__ partial,
                                              const float* __restrict__ Zpart,
                                              float* __restrict__ extra) {
  int b = blockIdx.x;
  int c = threadIdx.x;    // 0..511
  float Zb = 0.0f;
#pragma unroll
  for (int k = 0; k < 16; ++k) Zb += Zpart[b * 16 + k];
  const float* p = partial + (size_t)b * NTAILB * 512 + c;
  float a0 = 0.f, a1 = 0.f, a2 = 0.f, a3 = 0.f;
#pragma unroll
  for (int j = 0; j < NTAILB; j += 4) {
    a0 += p[(size_t)(j + 0) * 512];
    a1 += p[(size_t)(j + 1) * 512];
    a2 += p[(size_t)(j + 2) * 512];
    a3 += p[(size_t)(j + 3) * 512];
  }
  extra[b * NC + c] = ((a0 + a1) + (a2 + a3)) / Zb;
}

extern "C" void kernel_launch(void* const* d_in, const int* in_sizes, int n_in,
                              void* d_out, int out_size, void* d_ws, size_t ws_size,
                              hipStream_t stream) {
  (void)in_sizes; (void)n_in; (void)out_size; (void)ws_size;
  const f32x4* tok = (const f32x4*)d_in[0];
  const float* ax = (const float*)d_in[1];
  const float* ay = (const float*)d_in[2];

  unsigned long long* key = (unsigned long long*)d_ws;
  int* rank = (int*)((char*)d_ws + 524288);
  float* w = (float*)((char*)d_ws + 786432);
  int* order = (int*)((char*)d_ws + 1048576);
  f32x4* partial = (f32x4*)((char*)d_ws + 1310720);
  float* scalars = (float*)((char*)d_ws + 3145728);
  float* alpha = scalars;
  float* beta = scalars + 16;
  unsigned* smaxu = (unsigned*)(scalars + 32);
  float* Zpart = scalars + 48;

  float* out = (float*)d_out;
  f32x4* sel = (f32x4*)out;                         // [16][2458][512]
  float* extra = out + (size_t)NB * NKEEP * NC;     // [16][1][512]
  float* mask = extra + (size_t)NB * NC;            // [16][4096]

  k_front<<<NB, 1024, 0, stream>>>(ax, ay, key, rank, alpha, beta, smaxu);
  k_rank<<<dim3(4, 8, NB), 256, 0, stream>>>(key, rank);
  k_mid<<<256, 256, 0, stream>>>(ax, ay, alpha, beta, rank, smaxu, w, mask, order, Zpart);
  k_perm<<<dim3(128, NB), 256, 0, stream>>>(tok, order, w, sel, partial);
  k_back<<<NB, 512, 0, stream>>>((const float*)partial, Zpart, extra);
}